// Round 5
// baseline (733.370 us; speedup 1.0000x reference)
//
#include <hip/hip_runtime.h>
#include <hip/hip_bf16.h>

#define NB   128   // batch
#define NF   32    // channels f
#define NN1  64    // template points
#define NN2  128   // label points
#define MT   16    // m-tile per block

__global__ __launch_bounds__(256)
void v2b_kernel(const float* __restrict__ xl,    // (B,32,128)
                const float* __restrict__ xo,    // (B,32,64)
                const float* __restrict__ txyz,  // (B,64,3)
                const float* __restrict__ mlp_w1, const float* __restrict__ mlp_s1, const float* __restrict__ mlp_t1,
                const float* __restrict__ mlp_w2, const float* __restrict__ mlp_s2, const float* __restrict__ mlp_t2,
                const float* __restrict__ gw_w1, const float* __restrict__ gw_b1,
                const float* __restrict__ gw_s,  const float* __restrict__ gw_t,
                const float* __restrict__ gw_w2, const float* __restrict__ gw_b2,
                const float* __restrict__ gm_w1, const float* __restrict__ gm_s1, const float* __restrict__ gm_t1,
                const float* __restrict__ gm_w2, const float* __restrict__ gm_s2, const float* __restrict__ gm_t2,
                const float* __restrict__ fl_w1, const float* __restrict__ fl_s1, const float* __restrict__ fl_t1,
                const float* __restrict__ fl_w2, const float* __restrict__ fl_b2,
                float* __restrict__ out)        // fp32 output (reference dtype)
{
    __shared__ float xo_s[NF][NN1];    // x_object tile
    __shared__ float yon_s[NF][NN1];   // -(gw_w1 . xo)
    __shared__ float txyz_s[3][NN1];
    __shared__ float na_s[NN1];
    __shared__ float xl_s[NF][MT];
    __shared__ float yl_s[NF][MT];     // gw_w1 . xl + gw_b1
    __shared__ float nb_s[MT];

    const int b   = blockIdx.x / (NN2 / MT);
    const int m0  = (blockIdx.x % (NN2 / MT)) * MT;
    const int tid = threadIdx.x;
    const int lane = tid & 63;
    const int wv   = tid >> 6;

    // ---- stage inputs ----
    const float* xob = xo + (size_t)b * NF * NN1;
    for (int i = tid; i < NF * NN1; i += 256) (&xo_s[0][0])[i] = xob[i];

    const float* tb = txyz + (size_t)b * NN1 * 3;
    if (tid < NN1 * 3) { int n = tid / 3, k = tid % 3; txyz_s[k][n] = tb[tid]; }

    const float* xlb = xl + (size_t)b * NF * NN2;
    for (int i = tid; i < NF * MT; i += 256) {
        int c = i / MT, j = i % MT;
        xl_s[c][j] = xlb[c * NN2 + m0 + j];
    }
    __syncthreads();

    // ---- norms ----
    if (tid < NN1) {
        float s = 0.f;
        #pragma unroll
        for (int c = 0; c < NF; ++c) { float v = xo_s[c][tid]; s += v * v; }
        na_s[tid] = sqrtf(s);
    } else if (tid < NN1 + MT) {
        int j = tid - NN1; float s = 0.f;
        #pragma unroll
        for (int c = 0; c < NF; ++c) { float v = xl_s[c][j]; s += v * v; }
        nb_s[j] = sqrtf(s);
    }

    // ---- precompute gw_w1 projections (algebraic split of conv on diff) ----
    for (int i = tid; i < NF * NN1; i += 256) {
        int o = i >> 6, n = i & 63;
        float s = 0.f;
        #pragma unroll
        for (int c = 0; c < NF; ++c) s += gw_w1[o * 32 + c] * xo_s[c][n];
        yon_s[o][n] = -s;
    }
    for (int i = tid; i < NF * MT; i += 256) {
        int o = i / MT, j = i % MT;
        float s = gw_b1[o];
        #pragma unroll
        for (int c = 0; c < NF; ++c) s += gw_w1[o * 32 + c] * xl_s[c][j];
        yl_s[o][j] = s;
    }
    __syncthreads();

    const int n = lane;

    for (int ml = 0; ml < 4; ++ml) {
        const int j = wv * 4 + ml;     // 0..15 within tile
        const int m = m0 + j;

        // ---- cosine similarity, lane n vs column m ----
        float num = 0.f;
        #pragma unroll
        for (int c = 0; c < NF; ++c) num += xo_s[c][n] * xl_s[c][j];
        float cosv = num / fmaxf(na_s[n] * nb_s[j], 1e-8f);

        // ---- wave max + first-index argmax over n ----
        float mv = cosv; int mi = n;
        #pragma unroll
        for (int s = 32; s > 0; s >>= 1) {
            float ov = __shfl_xor(mv, s);
            int   oi = __shfl_xor(mi, s);
            if (ov > mv || (ov == mv && oi < mi)) { mv = ov; mi = oi; }
        }

        // ---- 2D branch: g = leaky(gw_s*(W1.xl - W1.xo + b1) + gw_t, 0.2) ----
        float g[32];
        #pragma unroll
        for (int o = 0; o < 32; ++o) {
            float a = gw_s[o] * (yl_s[o][j] + yon_s[o][n]) + gw_t[o];
            g[o] = a > 0.f ? a : 0.2f * a;
        }

        // gate = sigmoid(W2.g + b2); feat = [txyz; gate*xo]
        float feat[35];
        feat[0] = txyz_s[0][n]; feat[1] = txyz_s[1][n]; feat[2] = txyz_s[2][n];
        #pragma unroll
        for (int o = 0; o < 32; ++o) {
            float z = gw_b2[o];
            #pragma unroll
            for (int c = 0; c < 32; ++c) z += gw_w2[o * 32 + c] * g[c];
            float w = 1.f / (1.f + __expf(-z));
            feat[3 + o] = w * xo_s[o][n];
        }

        // gm layer 1 (35 -> 32), no conv bias
        float m1[32];
        #pragma unroll
        for (int o = 0; o < 32; ++o) {
            float s = 0.f;
            #pragma unroll
            for (int c = 0; c < 35; ++c) s += gm_w1[o * 35 + c] * feat[c];
            s = gm_s1[o] * s + gm_t1[o];
            m1[o] = s > 0.f ? s : 0.f;
        }

        // gm layer 2 (32 -> 32), then per-channel max over n (wave reduce)
        float gp[32];
        #pragma unroll
        for (int o = 0; o < 32; ++o) {
            float s = 0.f;
            #pragma unroll
            for (int c = 0; c < 32; ++c) s += gm_w2[o * 32 + c] * m1[c];
            s = gm_s2[o] * s + gm_t2[o];
            gp[o] = s > 0.f ? s : 0.f;
        }
        #pragma unroll
        for (int o = 0; o < 32; ++o) {
            float v = gp[o];
            #pragma unroll
            for (int s = 32; s > 0; s >>= 1) v = fmaxf(v, __shfl_xor(v, s));
            gp[o] = v;   // all lanes now hold gpool[o] for this m
        }

        // ---- 1D branch ----
        // fusion = [max_cla, txyz[mi], xo[:,mi], xl[:,m]]  (68 ch)
        const int oc = lane & 31;
        float h1;
        {
            const float* w = mlp_w1 + oc * 68;
            float acc = w[0] * mv;
            #pragma unroll
            for (int k = 0; k < 3; ++k)  acc += w[1 + k]  * txyz_s[k][mi];
            #pragma unroll
            for (int c = 0; c < 32; ++c) acc += w[4 + c]  * xo_s[c][mi];
            #pragma unroll
            for (int c = 0; c < 32; ++c) acc += w[36 + c] * xl_s[c][j];
            acc = mlp_s1[oc] * acc + mlp_t1[oc];
            h1 = acc > 0.f ? acc : 0.f;
        }
        float h2;
        {
            const float* w = mlp_w2 + oc * 32;
            float acc = 0.f;
            #pragma unroll
            for (int c = 0; c < 32; ++c) acc += w[c] * __shfl(h1, c);
            acc = mlp_s2[oc] * acc + mlp_t2[oc];
            h2 = acc > 0.f ? acc : 0.f;
        }
        // fl layer 1: row i = lane, input = [h2(32); gpool(32)]
        float o1;
        {
            const float* w = fl_w1 + lane * 64;
            float acc = 0.f;
            #pragma unroll
            for (int c = 0; c < 32; ++c) acc += w[c]      * __shfl(h2, c);
            #pragma unroll
            for (int c = 0; c < 32; ++c) acc += w[32 + c] * gp[c];
            acc = fl_s1[lane] * acc + fl_t1[lane];
            o1 = acc > 0.f ? acc : 0.f;
        }
        // fl layer 2 + bias, store (fp32)
        {
            const float* w = fl_w2 + lane * 64;
            float acc = fl_b2[lane];
            #pragma unroll
            for (int c = 0; c < 64; ++c) acc += w[c] * __shfl(o1, c);
            out[(size_t)b * 64 * NN2 + (size_t)lane * NN2 + m] = acc;
        }
    }
}

extern "C" void kernel_launch(void* const* d_in, const int* in_sizes, int n_in,
                              void* d_out, int out_size, void* d_ws, size_t ws_size,
                              hipStream_t stream) {
    const float* xl     = (const float*)d_in[0];
    const float* xo     = (const float*)d_in[1];
    const float* txyz   = (const float*)d_in[2];
    const float* mlp_w1 = (const float*)d_in[3];
    const float* mlp_s1 = (const float*)d_in[4];
    const float* mlp_t1 = (const float*)d_in[5];
    const float* mlp_w2 = (const float*)d_in[6];
    const float* mlp_s2 = (const float*)d_in[7];
    const float* mlp_t2 = (const float*)d_in[8];
    const float* gw_w1  = (const float*)d_in[9];
    const float* gw_b1  = (const float*)d_in[10];
    const float* gw_s   = (const float*)d_in[11];
    const float* gw_t   = (const float*)d_in[12];
    const float* gw_w2  = (const float*)d_in[13];
    const float* gw_b2  = (const float*)d_in[14];
    const float* gm_w1  = (const float*)d_in[15];
    const float* gm_s1  = (const float*)d_in[16];
    const float* gm_t1  = (const float*)d_in[17];
    const float* gm_w2  = (const float*)d_in[18];
    const float* gm_s2  = (const float*)d_in[19];
    const float* gm_t2  = (const float*)d_in[20];
    const float* fl_w1  = (const float*)d_in[21];
    const float* fl_s1  = (const float*)d_in[22];
    const float* fl_t1  = (const float*)d_in[23];
    const float* fl_w2  = (const float*)d_in[24];
    const float* fl_b2  = (const float*)d_in[25];
    float* outp = (float*)d_out;

    const int B = in_sizes[0] / (NF * NN2);   // 128
    dim3 grid(B * (NN2 / MT));                // 1024 blocks
    v2b_kernel<<<grid, 256, 0, stream>>>(
        xl, xo, txyz,
        mlp_w1, mlp_s1, mlp_t1, mlp_w2, mlp_s2, mlp_t2,
        gw_w1, gw_b1, gw_s, gw_t, gw_w2, gw_b2,
        gm_w1, gm_s1, gm_t1, gm_w2, gm_s2, gm_t2,
        fl_w1, fl_s1, fl_t1, fl_w2, fl_b2,
        outp);
}

// Round 6
// 519.381 us; speedup vs baseline: 1.4120x; 1.4120x over previous
//
#include <hip/hip_runtime.h>

#define NF   32
#define NN1  64
#define NN2  128

// ---------------- K1: heavy 2D branch -> gpool[b][m][o] into d_ws ----------------
__global__ __launch_bounds__(256, 4)
void v2b_k1(const float* __restrict__ xl,    // (B,32,128)
            const float* __restrict__ xo,    // (B,32,64)
            const float* __restrict__ txyz,  // (B,64,3)
            const float* __restrict__ gw_w1, const float* __restrict__ gw_b1,
            const float* __restrict__ gw_s,  const float* __restrict__ gw_t,
            const float* __restrict__ gw_w2, const float* __restrict__ gw_b2,
            const float* __restrict__ gm_w1, const float* __restrict__ gm_s1, const float* __restrict__ gm_t1,
            const float* __restrict__ gm_w2, const float* __restrict__ gm_s2, const float* __restrict__ gm_t2,
            float* __restrict__ ws)          // (B,128,32) gpool, [b][m][o]
{
    __shared__ float xo_s[NF][NN1];    // 8 KB
    __shared__ float yon_s[NF][NN1];   // 8 KB : -(gw_w1 . xo)
    __shared__ float txyz_s[3][NN1];
    __shared__ float yl_s[NF][4];      // gw_w1 . xl + b1 for this block's 4 m's

    const int b   = blockIdx.x >> 5;         // 128 batches
    const int m0  = (blockIdx.x & 31) * 4;   // 32 m-tiles of 4
    const int tid = threadIdx.x;
    const int lane = tid & 63;
    const int wv   = tid >> 6;

    const float* xob = xo + (size_t)b * NF * NN1;
    for (int i = tid; i < NF * NN1; i += 256) (&xo_s[0][0])[i] = xob[i];
    const float* tb = txyz + (size_t)b * NN1 * 3;
    if (tid < NN1 * 3) { int nn = tid / 3, k = tid % 3; txyz_s[k][nn] = tb[tid]; }
    __syncthreads();

    // yon = -(gw_w1 . xo)
    for (int i = tid; i < NF * NN1; i += 256) {
        int o = i >> 6, nn = i & 63;
        float s = 0.f;
        #pragma unroll
        for (int c = 0; c < NF; ++c) s += gw_w1[o * 32 + c] * xo_s[c][nn];
        yon_s[o][nn] = -s;
    }
    // yl = gw_w1 . xl + b1 for the 4 m's
    if (tid < 128) {
        int o = tid >> 2, j = tid & 3;
        const float* xlb = xl + (size_t)b * NF * NN2 + (m0 + j);
        float s = gw_b1[o];
        #pragma unroll
        for (int c = 0; c < NF; ++c) s += gw_w1[o * 32 + c] * xlb[c * NN2];
        yl_s[o][j] = s;
    }
    __syncthreads();

    const int n = lane;          // template point
    const int j = wv;            // m within tile (1 m per wave)
    const int m = m0 + j;

    // g = leaky(gw_s*(W1.xl - W1.xo + b1) + gw_t, 0.2)
    float g[32];
    #pragma unroll
    for (int o = 0; o < 32; ++o) {
        float a = gw_s[o] * (yl_s[o][j] + yon_s[o][n]) + gw_t[o];
        g[o] = a > 0.f ? a : 0.2f * a;
    }

    // gate = sigmoid(W2.g + b2); feat = [txyz; gate*xo]
    float feat[35];
    feat[0] = txyz_s[0][n]; feat[1] = txyz_s[1][n]; feat[2] = txyz_s[2][n];
    #pragma unroll
    for (int o = 0; o < 32; ++o) {
        float z = gw_b2[o];
        #pragma unroll
        for (int c = 0; c < 32; ++c) z += gw_w2[o * 32 + c] * g[c];
        float w = 1.f / (1.f + __expf(-z));
        feat[3 + o] = w * xo_s[o][n];
    }

    // gm layer 1 (35 -> 32)
    float m1[32];
    #pragma unroll
    for (int o = 0; o < 32; ++o) {
        float s = 0.f;
        #pragma unroll
        for (int c = 0; c < 35; ++c) s += gm_w1[o * 35 + c] * feat[c];
        s = gm_s1[o] * s + gm_t1[o];
        m1[o] = s > 0.f ? s : 0.f;
    }

    // gm layer 2 (32 -> 32) + immediate 64-lane max-reduce per channel
    float myout = 0.f;
    #pragma unroll
    for (int o = 0; o < 32; ++o) {
        float v = 0.f;
        #pragma unroll
        for (int c = 0; c < 32; ++c) v += gm_w2[o * 32 + c] * m1[c];
        v = gm_s2[o] * v + gm_t2[o];
        v = v > 0.f ? v : 0.f;
        #pragma unroll
        for (int s = 32; s > 0; s >>= 1) v = fmaxf(v, __shfl_xor(v, s));
        if (lane == o) myout = v;    // lane o keeps gpool[o]
    }
    if (lane < 32)
        ws[(size_t)b * NN2 * 32 + (size_t)m * 32 + lane] = myout;   // coalesced 128B per wave
}

// ---------------- K2: cosine/argmax + 1D MLP + fusion layers ----------------
__global__ __launch_bounds__(256, 4)
void v2b_k2(const float* __restrict__ xl, const float* __restrict__ xo,
            const float* __restrict__ txyz,
            const float* __restrict__ mlp_w1, const float* __restrict__ mlp_s1, const float* __restrict__ mlp_t1,
            const float* __restrict__ mlp_w2, const float* __restrict__ mlp_s2, const float* __restrict__ mlp_t2,
            const float* __restrict__ fl_w1, const float* __restrict__ fl_s1, const float* __restrict__ fl_t1,
            const float* __restrict__ fl_w2, const float* __restrict__ fl_b2,
            const float* __restrict__ ws,    // gpool [b][m][o]
            float* __restrict__ out)
{
    __shared__ float xo_s[NF][NN1];
    __shared__ float txyz_s[3][NN1];
    __shared__ float na_s[NN1];
    __shared__ float xl_s[NF][16];
    __shared__ float nb_s[16];

    const int b   = blockIdx.x >> 3;         // 128 batches
    const int m0  = (blockIdx.x & 7) * 16;   // 8 m-tiles of 16
    const int tid = threadIdx.x;
    const int lane = tid & 63;
    const int wv   = tid >> 6;

    const float* xob = xo + (size_t)b * NF * NN1;
    for (int i = tid; i < NF * NN1; i += 256) (&xo_s[0][0])[i] = xob[i];
    const float* tb = txyz + (size_t)b * NN1 * 3;
    if (tid < NN1 * 3) { int nn = tid / 3, k = tid % 3; txyz_s[k][nn] = tb[tid]; }
    const float* xlb = xl + (size_t)b * NF * NN2;
    for (int i = tid; i < NF * 16; i += 256) {
        int c = i >> 4, jj = i & 15;
        xl_s[c][jj] = xlb[c * NN2 + m0 + jj];
    }
    __syncthreads();

    if (tid < NN1) {
        float s = 0.f;
        #pragma unroll
        for (int c = 0; c < NF; ++c) { float v = xo_s[c][tid]; s += v * v; }
        na_s[tid] = sqrtf(s);
    } else if (tid < NN1 + 16) {
        int jj = tid - NN1; float s = 0.f;
        #pragma unroll
        for (int c = 0; c < NF; ++c) { float v = xl_s[c][jj]; s += v * v; }
        nb_s[jj] = sqrtf(s);
    }
    __syncthreads();

    const int n = lane;
    for (int ml = 0; ml < 4; ++ml) {
        const int j = wv * 4 + ml;
        const int m = m0 + j;

        // cosine similarity + first-index argmax over n
        float num = 0.f;
        #pragma unroll
        for (int c = 0; c < NF; ++c) num += xo_s[c][n] * xl_s[c][j];
        float cosv = num / fmaxf(na_s[n] * nb_s[j], 1e-8f);
        float mv = cosv; int mi = n;
        #pragma unroll
        for (int s = 32; s > 0; s >>= 1) {
            float ov = __shfl_xor(mv, s);
            int   oi = __shfl_xor(mi, s);
            if (ov > mv || (ov == mv && oi < mi)) { mv = ov; mi = oi; }
        }

        const int oc = lane & 31;
        float h1;
        {
            const float* w = mlp_w1 + oc * 68;
            float acc = w[0] * mv;
            #pragma unroll
            for (int k = 0; k < 3; ++k)  acc += w[1 + k]  * txyz_s[k][mi];
            #pragma unroll
            for (int c = 0; c < 32; ++c) acc += w[4 + c]  * xo_s[c][mi];
            #pragma unroll
            for (int c = 0; c < 32; ++c) acc += w[36 + c] * xl_s[c][j];
            acc = mlp_s1[oc] * acc + mlp_t1[oc];
            h1 = acc > 0.f ? acc : 0.f;
        }
        float h2;
        {
            const float* w = mlp_w2 + oc * 32;
            float acc = 0.f;
            #pragma unroll
            for (int c = 0; c < 32; ++c) acc += w[c] * __shfl(h1, c);
            acc = mlp_s2[oc] * acc + mlp_t2[oc];
            h2 = acc > 0.f ? acc : 0.f;
        }
        float o1;
        {
            const float* w  = fl_w1 + lane * 64;
            const float* gp = ws + (size_t)b * NN2 * 32 + (size_t)m * 32;  // wave-uniform -> s_load
            float acc = 0.f;
            #pragma unroll
            for (int c = 0; c < 32; ++c) acc += w[c]      * __shfl(h2, c);
            #pragma unroll
            for (int c = 0; c < 32; ++c) acc += w[32 + c] * gp[c];
            acc = fl_s1[lane] * acc + fl_t1[lane];
            o1 = acc > 0.f ? acc : 0.f;
        }
        {
            const float* w = fl_w2 + lane * 64;
            float acc = fl_b2[lane];
            #pragma unroll
            for (int c = 0; c < 64; ++c) acc += w[c] * __shfl(o1, c);
            out[(size_t)b * 64 * NN2 + (size_t)lane * NN2 + m] = acc;
        }
    }
}

extern "C" void kernel_launch(void* const* d_in, const int* in_sizes, int n_in,
                              void* d_out, int out_size, void* d_ws, size_t ws_size,
                              hipStream_t stream) {
    const float* xl     = (const float*)d_in[0];
    const float* xo     = (const float*)d_in[1];
    const float* txyz   = (const float*)d_in[2];
    const float* mlp_w1 = (const float*)d_in[3];
    const float* mlp_s1 = (const float*)d_in[4];
    const float* mlp_t1 = (const float*)d_in[5];
    const float* mlp_w2 = (const float*)d_in[6];
    const float* mlp_s2 = (const float*)d_in[7];
    const float* mlp_t2 = (const float*)d_in[8];
    const float* gw_w1  = (const float*)d_in[9];
    const float* gw_b1  = (const float*)d_in[10];
    const float* gw_s   = (const float*)d_in[11];
    const float* gw_t   = (const float*)d_in[12];
    const float* gw_w2  = (const float*)d_in[13];
    const float* gw_b2  = (const float*)d_in[14];
    const float* gm_w1  = (const float*)d_in[15];
    const float* gm_s1  = (const float*)d_in[16];
    const float* gm_t1  = (const float*)d_in[17];
    const float* gm_w2  = (const float*)d_in[18];
    const float* gm_s2  = (const float*)d_in[19];
    const float* gm_t2  = (const float*)d_in[20];
    const float* fl_w1  = (const float*)d_in[21];
    const float* fl_s1  = (const float*)d_in[22];
    const float* fl_t1  = (const float*)d_in[23];
    const float* fl_w2  = (const float*)d_in[24];
    const float* fl_b2  = (const float*)d_in[25];
    float* outp = (float*)d_out;
    float* wsp  = (float*)d_ws;      // needs B*128*32*4 = 2 MB

    const int B = in_sizes[0] / (NF * NN2);   // 128

    v2b_k1<<<dim3(B * 32), 256, 0, stream>>>(
        xl, xo, txyz,
        gw_w1, gw_b1, gw_s, gw_t, gw_w2, gw_b2,
        gm_w1, gm_s1, gm_t1, gm_w2, gm_s2, gm_t2,
        wsp);

    v2b_k2<<<dim3(B * 8), 256, 0, stream>>>(
        xl, xo, txyz,
        mlp_w1, mlp_s1, mlp_t1, mlp_w2, mlp_s2, mlp_t2,
        fl_w1, fl_s1, fl_t1, fl_w2, fl_b2,
        wsp, outp);
}

// Round 7
// 356.858 us; speedup vs baseline: 2.0551x; 1.4554x over previous
//
#include <hip/hip_runtime.h>

#define NF   32
#define NN1  64
#define NN2  128

// Fused single kernel: Phase A (2D attention branch, wave=m lane=n) -> gp_s in LDS
//                      Phase B (cosine/argmax + 1D MLP + fusion, wave=m lane=ch)
// __launch_bounds__(256,4): cap VGPR at 128 (round-5 lesson: uncapped -> 256 VGPR, 1 wave/SIMD)
__global__ __launch_bounds__(256, 4)
void v2b_fused(const float* __restrict__ xl,    // (B,32,128)
               const float* __restrict__ xo,    // (B,32,64)
               const float* __restrict__ txyz,  // (B,64,3)
               const float* __restrict__ mlp_w1, const float* __restrict__ mlp_s1, const float* __restrict__ mlp_t1,
               const float* __restrict__ mlp_w2, const float* __restrict__ mlp_s2, const float* __restrict__ mlp_t2,
               const float* __restrict__ gw_w1, const float* __restrict__ gw_b1,
               const float* __restrict__ gw_s,  const float* __restrict__ gw_t,
               const float* __restrict__ gw_w2, const float* __restrict__ gw_b2,
               const float* __restrict__ gm_w1, const float* __restrict__ gm_s1, const float* __restrict__ gm_t1,
               const float* __restrict__ gm_w2, const float* __restrict__ gm_s2, const float* __restrict__ gm_t2,
               const float* __restrict__ fl_w1, const float* __restrict__ fl_s1, const float* __restrict__ fl_t1,
               const float* __restrict__ fl_w2, const float* __restrict__ fl_b2,
               float* __restrict__ out)
{
    __shared__ float xo_s[NF][NN1];    // 8 KB
    __shared__ float yon_s[NF][NN1];   // 8 KB : -(gw_w1 . xo)
    __shared__ float txyz_s[3][NN1];
    __shared__ float yl_s[NF][4];      // gw_w1 . xl + b1 for the 4 m's
    __shared__ float xl_s[NF][4];      // xl columns for the 4 m's
    __shared__ float na_s[NN1];
    __shared__ float nb_s[4];
    __shared__ float gp_s[4][NF];      // gpool per m

    const int b   = blockIdx.x >> 5;         // 128 batches
    const int m0  = (blockIdx.x & 31) * 4;   // 32 m-tiles of 4
    const int tid = threadIdx.x;
    const int lane = tid & 63;
    const int wv   = tid >> 6;

    // ---- stage ----
    const float* xob = xo + (size_t)b * NF * NN1;
    for (int i = tid; i < NF * NN1; i += 256) (&xo_s[0][0])[i] = xob[i];
    const float* tb = txyz + (size_t)b * NN1 * 3;
    if (tid < NN1 * 3) { int nn = tid / 3, k = tid % 3; txyz_s[k][nn] = tb[tid]; }
    if (tid < NF * 4) {
        int c = tid >> 2, j = tid & 3;
        xl_s[c][j] = xl[(size_t)b * NF * NN2 + c * NN2 + m0 + j];
    }
    __syncthreads();

    // ---- precompute: yon (8/thread), yl (tid<128), na (128..191), nb (192..195) ----
    for (int i = tid; i < NF * NN1; i += 256) {
        int o = i >> 6, nn = i & 63;
        float s = 0.f;
        #pragma unroll
        for (int c = 0; c < NF; ++c) s += gw_w1[o * 32 + c] * xo_s[c][nn];
        yon_s[o][nn] = -s;
    }
    if (tid < 128) {
        int o = tid >> 2, j = tid & 3;
        float s = gw_b1[o];
        #pragma unroll
        for (int c = 0; c < NF; ++c) s += gw_w1[o * 32 + c] * xl_s[c][j];
        yl_s[o][j] = s;
    } else if (tid < 192) {
        int nn = tid - 128;
        float s = 0.f;
        #pragma unroll
        for (int c = 0; c < NF; ++c) { float v = xo_s[c][nn]; s += v * v; }
        na_s[nn] = sqrtf(s);
    } else if (tid < 196) {
        int j = tid - 192;
        float s = 0.f;
        #pragma unroll
        for (int c = 0; c < NF; ++c) { float v = xl_s[c][j]; s += v * v; }
        nb_s[j] = sqrtf(s);
    }
    __syncthreads();

    const int n = lane;          // template point
    const int j = wv;            // m within tile (1 m per wave)
    const int m = m0 + j;

    // ---- Phase A: 2D branch ----
    {
        // g = leaky(gw_s*(W1.xl - W1.xo + b1) + gw_t, 0.2)
        float g[32];
        #pragma unroll
        for (int o = 0; o < 32; ++o) {
            float a = gw_s[o] * (yl_s[o][j] + yon_s[o][n]) + gw_t[o];
            g[o] = a > 0.f ? a : 0.2f * a;
        }
        // gate = sigmoid(W2.g + b2); feat = [txyz; gate*xo]
        float feat[35];
        feat[0] = txyz_s[0][n]; feat[1] = txyz_s[1][n]; feat[2] = txyz_s[2][n];
        #pragma unroll
        for (int o = 0; o < 32; ++o) {
            float z = gw_b2[o];
            #pragma unroll
            for (int c = 0; c < 32; ++c) z += gw_w2[o * 32 + c] * g[c];
            float w = 1.f / (1.f + __expf(-z));
            feat[3 + o] = w * xo_s[o][n];
        }
        // gm layer 1 (35 -> 32)
        float m1[32];
        #pragma unroll
        for (int o = 0; o < 32; ++o) {
            float s = 0.f;
            #pragma unroll
            for (int c = 0; c < 35; ++c) s += gm_w1[o * 35 + c] * feat[c];
            s = gm_s1[o] * s + gm_t1[o];
            m1[o] = s > 0.f ? s : 0.f;
        }
        // gm layer 2 (32 -> 32) + immediate 64-lane max-reduce per channel
        float myout = 0.f;
        #pragma unroll
        for (int o = 0; o < 32; ++o) {
            float v = 0.f;
            #pragma unroll
            for (int c = 0; c < 32; ++c) v += gm_w2[o * 32 + c] * m1[c];
            v = gm_s2[o] * v + gm_t2[o];
            v = v > 0.f ? v : 0.f;
            #pragma unroll
            for (int s = 32; s > 0; s >>= 1) v = fmaxf(v, __shfl_xor(v, s));
            if (lane == o) myout = v;    // lane o keeps gpool[o]
        }
        if (lane < 32) gp_s[j][lane] = myout;
    }
    __syncthreads();

    // ---- Phase B: cosine/argmax + 1D MLP + fusion ----
    float num = 0.f;
    #pragma unroll
    for (int c = 0; c < NF; ++c) num += xo_s[c][n] * xl_s[c][j];
    float cosv = num / fmaxf(na_s[n] * nb_s[j], 1e-8f);
    float mv = cosv; int mi = n;
    #pragma unroll
    for (int s = 32; s > 0; s >>= 1) {
        float ov = __shfl_xor(mv, s);
        int   oi = __shfl_xor(mi, s);
        if (ov > mv || (ov == mv && oi < mi)) { mv = ov; mi = oi; }
    }

    const int oc = lane & 31;
    float h1;
    {
        const float* w = mlp_w1 + oc * 68;
        float acc = w[0] * mv;
        #pragma unroll
        for (int k = 0; k < 3; ++k)  acc += w[1 + k]  * txyz_s[k][mi];
        #pragma unroll
        for (int c = 0; c < 32; ++c) acc += w[4 + c]  * xo_s[c][mi];
        #pragma unroll
        for (int c = 0; c < 32; ++c) acc += w[36 + c] * xl_s[c][j];
        acc = mlp_s1[oc] * acc + mlp_t1[oc];
        h1 = acc > 0.f ? acc : 0.f;
    }
    float h2;
    {
        const float* w = mlp_w2 + oc * 32;
        float acc = 0.f;
        #pragma unroll
        for (int c = 0; c < 32; ++c) acc += w[c] * __shfl(h1, c);
        acc = mlp_s2[oc] * acc + mlp_t2[oc];
        h2 = acc > 0.f ? acc : 0.f;
    }
    float o1;
    {
        const float* w = fl_w1 + lane * 64;
        float acc = 0.f;
        #pragma unroll
        for (int c = 0; c < 32; ++c) acc += w[c]      * __shfl(h2, c);
        #pragma unroll
        for (int c = 0; c < 32; ++c) acc += w[32 + c] * gp_s[j][c];
        acc = fl_s1[lane] * acc + fl_t1[lane];
        o1 = acc > 0.f ? acc : 0.f;
    }
    {
        const float* w = fl_w2 + lane * 64;
        float acc = fl_b2[lane];
        #pragma unroll
        for (int c = 0; c < 64; ++c) acc += w[c] * __shfl(o1, c);
        out[(size_t)b * 64 * NN2 + (size_t)lane * NN2 + m] = acc;
    }
}

extern "C" void kernel_launch(void* const* d_in, const int* in_sizes, int n_in,
                              void* d_out, int out_size, void* d_ws, size_t ws_size,
                              hipStream_t stream) {
    const float* xl     = (const float*)d_in[0];
    const float* xo     = (const float*)d_in[1];
    const float* txyz   = (const float*)d_in[2];
    const float* mlp_w1 = (const float*)d_in[3];
    const float* mlp_s1 = (const float*)d_in[4];
    const float* mlp_t1 = (const float*)d_in[5];
    const float* mlp_w2 = (const float*)d_in[6];
    const float* mlp_s2 = (const float*)d_in[7];
    const float* mlp_t2 = (const float*)d_in[8];
    const float* gw_w1  = (const float*)d_in[9];
    const float* gw_b1  = (const float*)d_in[10];
    const float* gw_s   = (const float*)d_in[11];
    const float* gw_t   = (const float*)d_in[12];
    const float* gw_w2  = (const float*)d_in[13];
    const float* gw_b2  = (const float*)d_in[14];
    const float* gm_w1  = (const float*)d_in[15];
    const float* gm_s1  = (const float*)d_in[16];
    const float* gm_t1  = (const float*)d_in[17];
    const float* gm_w2  = (const float*)d_in[18];
    const float* gm_s2  = (const float*)d_in[19];
    const float* gm_t2  = (const float*)d_in[20];
    const float* fl_w1  = (const float*)d_in[21];
    const float* fl_s1  = (const float*)d_in[22];
    const float* fl_t1  = (const float*)d_in[23];
    const float* fl_w2  = (const float*)d_in[24];
    const float* fl_b2  = (const float*)d_in[25];
    float* outp = (float*)d_out;

    const int B = in_sizes[0] / (NF * NN2);   // 128
    v2b_fused<<<dim3(B * 32), 256, 0, stream>>>(
        xl, xo, txyz,
        mlp_w1, mlp_s1, mlp_t1, mlp_w2, mlp_s2, mlp_t2,
        gw_w1, gw_b1, gw_s, gw_t, gw_w2, gw_b2,
        gm_w1, gm_s1, gm_t1, gm_w2, gm_s2, gm_t2,
        fl_w1, fl_s1, fl_t1, fl_w2, fl_b2,
        outp);
}

// Round 8
// 328.248 us; speedup vs baseline: 2.2342x; 1.0872x over previous
//
#include <hip/hip_runtime.h>

#define NF   32
#define NN1  64
#define NN2  128

// Fused single kernel: Phase A (2D attention branch, wave=m lane=n) -> gp_s in LDS
//                      Phase B (cosine/argmax + 1D MLP + fusion, wave=m lane=ch)
// waves_per_eu(4,4): EXACTLY 4 waves/EU -> 128-VGPR budget. R7 lesson: (256,4) as a
// min let the allocator chase the 8-waves bucket (VGPR=64) and spill ~20 slots
// (81 MB/dispatch scratch writebacks).
__global__ __launch_bounds__(256) __attribute__((amdgpu_waves_per_eu(4, 4)))
void v2b_fused(const float* __restrict__ xl,    // (B,32,128)
               const float* __restrict__ xo,    // (B,32,64)
               const float* __restrict__ txyz,  // (B,64,3)
               const float* __restrict__ mlp_w1, const float* __restrict__ mlp_s1, const float* __restrict__ mlp_t1,
               const float* __restrict__ mlp_w2, const float* __restrict__ mlp_s2, const float* __restrict__ mlp_t2,
               const float* __restrict__ gw_w1, const float* __restrict__ gw_b1,
               const float* __restrict__ gw_s,  const float* __restrict__ gw_t,
               const float* __restrict__ gw_w2, const float* __restrict__ gw_b2,
               const float* __restrict__ gm_w1, const float* __restrict__ gm_s1, const float* __restrict__ gm_t1,
               const float* __restrict__ gm_w2, const float* __restrict__ gm_s2, const float* __restrict__ gm_t2,
               const float* __restrict__ fl_w1, const float* __restrict__ fl_s1, const float* __restrict__ fl_t1,
               const float* __restrict__ fl_w2, const float* __restrict__ fl_b2,
               float* __restrict__ out)
{
    __shared__ float xo_s[NF][NN1];    // 8 KB
    __shared__ float yon_s[NF][NN1];   // 8 KB : -(gw_w1 . xo)
    __shared__ float txyz_s[3][NN1];
    __shared__ float yl_s[NF][4];      // gw_w1 . xl + b1 for the 4 m's
    __shared__ float xl_s[NF][4];      // xl columns for the 4 m's
    __shared__ float na_s[NN1];
    __shared__ float nb_s[4];
    __shared__ float gp_s[4][NF];      // gpool per m

    const int b   = blockIdx.x >> 5;         // 128 batches
    const int m0  = (blockIdx.x & 31) * 4;   // 32 m-tiles of 4
    const int tid = threadIdx.x;
    const int lane = tid & 63;
    const int wv   = tid >> 6;

    // ---- stage ----
    const float* xob = xo + (size_t)b * NF * NN1;
    for (int i = tid; i < NF * NN1; i += 256) (&xo_s[0][0])[i] = xob[i];
    const float* tb = txyz + (size_t)b * NN1 * 3;
    if (tid < NN1 * 3) { int nn = tid / 3, k = tid % 3; txyz_s[k][nn] = tb[tid]; }
    if (tid < NF * 4) {
        int c = tid >> 2, j = tid & 3;
        xl_s[c][j] = xl[(size_t)b * NF * NN2 + c * NN2 + m0 + j];
    }
    __syncthreads();

    // ---- precompute: yon (8/thread), yl (tid<128), na (128..191), nb (192..195) ----
    for (int i = tid; i < NF * NN1; i += 256) {
        int o = i >> 6, nn = i & 63;
        float s = 0.f;
        #pragma unroll
        for (int c = 0; c < NF; ++c) s += gw_w1[o * 32 + c] * xo_s[c][nn];
        yon_s[o][nn] = -s;
    }
    if (tid < 128) {
        int o = tid >> 2, j = tid & 3;
        float s = gw_b1[o];
        #pragma unroll
        for (int c = 0; c < NF; ++c) s += gw_w1[o * 32 + c] * xl_s[c][j];
        yl_s[o][j] = s;
    } else if (tid < 192) {
        int nn = tid - 128;
        float s = 0.f;
        #pragma unroll
        for (int c = 0; c < NF; ++c) { float v = xo_s[c][nn]; s += v * v; }
        na_s[nn] = sqrtf(s);
    } else if (tid < 196) {
        int j = tid - 192;
        float s = 0.f;
        #pragma unroll
        for (int c = 0; c < NF; ++c) { float v = xl_s[c][j]; s += v * v; }
        nb_s[j] = sqrtf(s);
    }
    __syncthreads();

    const int n = lane;          // template point
    const int j = wv;            // m within tile (1 m per wave)
    const int m = m0 + j;

    // ---- Phase A: 2D branch ----
    {
        // g = leaky(gw_s*(W1.xl - W1.xo + b1) + gw_t, 0.2)
        float g[32];
        #pragma unroll
        for (int o = 0; o < 32; ++o) {
            float a = gw_s[o] * (yl_s[o][j] + yon_s[o][n]) + gw_t[o];
            g[o] = a > 0.f ? a : 0.2f * a;
        }
        // gate = sigmoid(W2.g + b2); feat = [txyz; gate*xo]
        float feat[35];
        feat[0] = txyz_s[0][n]; feat[1] = txyz_s[1][n]; feat[2] = txyz_s[2][n];
        #pragma unroll
        for (int o = 0; o < 32; ++o) {
            float z = gw_b2[o];
            #pragma unroll
            for (int c = 0; c < 32; ++c) z += gw_w2[o * 32 + c] * g[c];
            float w = 1.f / (1.f + __expf(-z));
            feat[3 + o] = w * xo_s[o][n];
        }
        // gm layer 1 (35 -> 32)
        float m1[32];
        #pragma unroll
        for (int o = 0; o < 32; ++o) {
            float s = 0.f;
            #pragma unroll
            for (int c = 0; c < 35; ++c) s += gm_w1[o * 35 + c] * feat[c];
            s = gm_s1[o] * s + gm_t1[o];
            m1[o] = s > 0.f ? s : 0.f;
        }
        // gm layer 2 (32 -> 32) + immediate 64-lane max-reduce per channel
        float myout = 0.f;
        #pragma unroll
        for (int o = 0; o < 32; ++o) {
            float v = 0.f;
            #pragma unroll
            for (int c = 0; c < 32; ++c) v += gm_w2[o * 32 + c] * m1[c];
            v = gm_s2[o] * v + gm_t2[o];
            v = v > 0.f ? v : 0.f;
            #pragma unroll
            for (int s = 32; s > 0; s >>= 1) v = fmaxf(v, __shfl_xor(v, s));
            if (lane == o) myout = v;    // lane o keeps gpool[o]
        }
        if (lane < 32) gp_s[j][lane] = myout;
    }
    __syncthreads();

    // ---- Phase B: cosine/argmax + 1D MLP + fusion ----
    float num = 0.f;
    #pragma unroll
    for (int c = 0; c < NF; ++c) num += xo_s[c][n] * xl_s[c][j];
    float cosv = num / fmaxf(na_s[n] * nb_s[j], 1e-8f);
    float mv = cosv; int mi = n;
    #pragma unroll
    for (int s = 32; s > 0; s >>= 1) {
        float ov = __shfl_xor(mv, s);
        int   oi = __shfl_xor(mi, s);
        if (ov > mv || (ov == mv && oi < mi)) { mv = ov; mi = oi; }
    }

    const int oc = lane & 31;
    float h1;
    {
        const float* w = mlp_w1 + oc * 68;
        float acc = w[0] * mv;
        #pragma unroll
        for (int k = 0; k < 3; ++k)  acc += w[1 + k]  * txyz_s[k][mi];
        #pragma unroll
        for (int c = 0; c < 32; ++c) acc += w[4 + c]  * xo_s[c][mi];
        #pragma unroll
        for (int c = 0; c < 32; ++c) acc += w[36 + c] * xl_s[c][j];
        acc = mlp_s1[oc] * acc + mlp_t1[oc];
        h1 = acc > 0.f ? acc : 0.f;
    }
    float h2;
    {
        const float* w = mlp_w2 + oc * 32;
        float acc = 0.f;
        #pragma unroll
        for (int c = 0; c < 32; ++c) acc += w[c] * __shfl(h1, c);
        acc = mlp_s2[oc] * acc + mlp_t2[oc];
        h2 = acc > 0.f ? acc : 0.f;
    }
    float o1;
    {
        const float* w = fl_w1 + lane * 64;
        float acc = 0.f;
        #pragma unroll
        for (int c = 0; c < 32; ++c) acc += w[c]      * __shfl(h2, c);
        #pragma unroll
        for (int c = 0; c < 32; ++c) acc += w[32 + c] * gp_s[j][c];
        acc = fl_s1[lane] * acc + fl_t1[lane];
        o1 = acc > 0.f ? acc : 0.f;
    }
    {
        const float* w = fl_w2 + lane * 64;
        float acc = fl_b2[lane];
        #pragma unroll
        for (int c = 0; c < 64; ++c) acc += w[c] * __shfl(o1, c);
        out[(size_t)b * 64 * NN2 + (size_t)lane * NN2 + m] = acc;
    }
}

extern "C" void kernel_launch(void* const* d_in, const int* in_sizes, int n_in,
                              void* d_out, int out_size, void* d_ws, size_t ws_size,
                              hipStream_t stream) {
    const float* xl     = (const float*)d_in[0];
    const float* xo     = (const float*)d_in[1];
    const float* txyz   = (const float*)d_in[2];
    const float* mlp_w1 = (const float*)d_in[3];
    const float* mlp_s1 = (const float*)d_in[4];
    const float* mlp_t1 = (const float*)d_in[5];
    const float* mlp_w2 = (const float*)d_in[6];
    const float* mlp_s2 = (const float*)d_in[7];
    const float* mlp_t2 = (const float*)d_in[8];
    const float* gw_w1  = (const float*)d_in[9];
    const float* gw_b1  = (const float*)d_in[10];
    const float* gw_s   = (const float*)d_in[11];
    const float* gw_t   = (const float*)d_in[12];
    const float* gw_w2  = (const float*)d_in[13];
    const float* gw_b2  = (const float*)d_in[14];
    const float* gm_w1  = (const float*)d_in[15];
    const float* gm_s1  = (const float*)d_in[16];
    const float* gm_t1  = (const float*)d_in[17];
    const float* gm_w2  = (const float*)d_in[18];
    const float* gm_s2  = (const float*)d_in[19];
    const float* gm_t2  = (const float*)d_in[20];
    const float* fl_w1  = (const float*)d_in[21];
    const float* fl_s1  = (const float*)d_in[22];
    const float* fl_t1  = (const float*)d_in[23];
    const float* fl_w2  = (const float*)d_in[24];
    const float* fl_b2  = (const float*)d_in[25];
    float* outp = (float*)d_out;

    const int B = in_sizes[0] / (NF * NN2);   // 128
    v2b_fused<<<dim3(B * 32), 256, 0, stream>>>(
        xl, xo, txyz,
        mlp_w1, mlp_s1, mlp_t1, mlp_w2, mlp_s2, mlp_t2,
        gw_w1, gw_b1, gw_s, gw_t, gw_w2, gw_b2,
        gm_w1, gm_s1, gm_t1, gm_w2, gm_s2, gm_t2,
        fl_w1, fl_s1, fl_t1, fl_w2, fl_b2,
        outp);
}

// Round 9
// 304.743 us; speedup vs baseline: 2.4065x; 1.0771x over previous
//
#include <hip/hip_runtime.h>

#define NF   32
#define NN1  64
#define NN2  128

typedef float f32x4 __attribute__((ext_vector_type(4)));
typedef short s16x8 __attribute__((ext_vector_type(8)));

__device__ __forceinline__ short f2bf(float f) {   // fp32 -> bf16 bits, RNE
    unsigned u = __float_as_uint(f);
    unsigned r = (u + 0x7FFFu + ((u >> 16) & 1u)) >> 16;
    return (short)r;
}

// Phase A on MFMA: per wave (one m), loop 4 n-groups of 16.
//  gate:  z = gw_w2 @ g + b2          (2 mfma, C-init = b2)
//  gm1 :  m1 = relu(s1*(W@feat)+t1)   (2 mfma, s1 folded in A, t1+txyz-part in C-init)
//  gm2 :  m2 = relu(s2*(W@m1)+t2)     (2 mfma, s2 in A, t2 in C-init)
// A-layout: lane holds A[l%16][8*(l/16)+j]; B: B[8*(l/16)+j][l%16];
// C/D (m89-verified): col=l&15, row=(l>>4)*4+reg.
__global__ __launch_bounds__(256) __attribute__((amdgpu_waves_per_eu(4, 4)))
void v2b_fused(const float* __restrict__ xl,    // (B,32,128)
               const float* __restrict__ xo,    // (B,32,64)
               const float* __restrict__ txyz,  // (B,64,3)
               const float* __restrict__ mlp_w1, const float* __restrict__ mlp_s1, const float* __restrict__ mlp_t1,
               const float* __restrict__ mlp_w2, const float* __restrict__ mlp_s2, const float* __restrict__ mlp_t2,
               const float* __restrict__ gw_w1, const float* __restrict__ gw_b1,
               const float* __restrict__ gw_s,  const float* __restrict__ gw_t,
               const float* __restrict__ gw_w2, const float* __restrict__ gw_b2,
               const float* __restrict__ gm_w1, const float* __restrict__ gm_s1, const float* __restrict__ gm_t1,
               const float* __restrict__ gm_w2, const float* __restrict__ gm_s2, const float* __restrict__ gm_t2,
               const float* __restrict__ fl_w1, const float* __restrict__ fl_s1, const float* __restrict__ fl_t1,
               const float* __restrict__ fl_w2, const float* __restrict__ fl_b2,
               float* __restrict__ out)
{
    __shared__ float xo_s[NF][65];     // stride-65 pad: bank = (c+n)%32
    __shared__ float yon_s[NF][65];    // -(gw_w1 . xo)
    __shared__ float tpos_s[NF][65];   // t1 + s1*(gm_w1[:,0:3] . txyz)
    __shared__ float txyz_s[3][NN1];
    __shared__ float xl_s[NF][4];
    __shared__ float ylT_s[4][NF];     // gw_w1 . xl + b1, [m][c]
    __shared__ float na_s[NN1];
    __shared__ float nb_s[4];
    __shared__ float gp_s[4][NF];
    __shared__ short bnc_s[4][16][40]; // per-wave bounce [col][row] bf16, pitch 40

    const int b    = blockIdx.x >> 5;
    const int m0   = (blockIdx.x & 31) * 4;
    const int tid  = threadIdx.x;
    const int lane = tid & 63;
    const int wv   = tid >> 6;
    const int colr = lane & 15;
    const int q    = lane >> 4;

    // ---- A-frags + per-lane constants (pure global, hides under staging) ----
    s16x8 a_gw2_lo, a_gw2_hi, a_gm1_lo, a_gm1_hi, a_gm2_lo, a_gm2_hi;
    {
        const float s1lo = gm_s1[colr], s1hi = gm_s1[colr + 16];
        const float s2lo = gm_s2[colr], s2hi = gm_s2[colr + 16];
        #pragma unroll
        for (int jx = 0; jx < 8; ++jx) {
            const int k = 8 * q + jx;
            a_gw2_lo[jx] = f2bf(gw_w2[colr * 32 + k]);
            a_gw2_hi[jx] = f2bf(gw_w2[(colr + 16) * 32 + k]);
            a_gm1_lo[jx] = f2bf(s1lo * gm_w1[colr * 35 + 3 + k]);
            a_gm1_hi[jx] = f2bf(s1hi * gm_w1[(colr + 16) * 35 + 3 + k]);
            a_gm2_lo[jx] = f2bf(s2lo * gm_w2[colr * 32 + k]);
            a_gm2_hi[jx] = f2bf(s2hi * gm_w2[(colr + 16) * 32 + k]);
        }
    }
    float gwsv[8], gwtv[8], b2i[8], t2i[8];
    #pragma unroll
    for (int jx = 0; jx < 8; ++jx) { gwsv[jx] = gw_s[8 * q + jx]; gwtv[jx] = gw_t[8 * q + jx]; }
    #pragma unroll
    for (int ix = 0; ix < 8; ++ix) {
        const int row = 4 * q + (ix & 3) + 16 * (ix >> 2);
        b2i[ix] = gw_b2[row];
        t2i[ix] = gm_t2[row];
    }

    // ---- stage ----
    const float* xob = xo + (size_t)b * NF * NN1;
    for (int i = tid; i < NF * NN1; i += 256) xo_s[i >> 6][i & 63] = xob[i];
    const float* tb = txyz + (size_t)b * NN1 * 3;
    if (tid < NN1 * 3) { int nn = tid / 3, k = tid % 3; txyz_s[k][nn] = tb[tid]; }
    if (tid < NF * 4) {
        int c = tid >> 2, j = tid & 3;
        xl_s[c][j] = xl[(size_t)b * NF * NN2 + c * NN2 + m0 + j];
    }
    __syncthreads();

    // ---- block precompute ----
    for (int i = tid; i < NF * NN1; i += 256) {
        const int o = i >> 6, nn = i & 63;
        float s = 0.f;
        #pragma unroll
        for (int c = 0; c < NF; ++c) s += gw_w1[o * 32 + c] * xo_s[c][nn];
        yon_s[o][nn] = -s;
        float tp = gm_w1[o * 35 + 0] * txyz_s[0][nn]
                 + gm_w1[o * 35 + 1] * txyz_s[1][nn]
                 + gm_w1[o * 35 + 2] * txyz_s[2][nn];
        tpos_s[o][nn] = gm_s1[o] * tp + gm_t1[o];
    }
    if (tid < 128) {
        const int o = tid >> 2, j = tid & 3;
        float s = gw_b1[o];
        #pragma unroll
        for (int c = 0; c < NF; ++c) s += gw_w1[o * 32 + c] * xl_s[c][j];
        ylT_s[j][o] = s;
    } else if (tid < 192) {
        const int nn = tid - 128;
        float s = 0.f;
        #pragma unroll
        for (int c = 0; c < NF; ++c) { float v = xo_s[c][nn]; s += v * v; }
        na_s[nn] = sqrtf(s);
    } else if (tid < 196) {
        const int j = tid - 192;
        float s = 0.f;
        #pragma unroll
        for (int c = 0; c < NF; ++c) { float v = xl_s[c][j]; s += v * v; }
        nb_s[j] = sqrtf(s);
    }
    __syncthreads();

    const int mj = wv;
    const int m  = m0 + wv;

    // ---- Phase A (MFMA) ----
    float ylv[8];
    #pragma unroll
    for (int jx = 0; jx < 8; ++jx) ylv[jx] = ylT_s[mj][8 * q + jx];

    float rmax[8] = {0.f, 0.f, 0.f, 0.f, 0.f, 0.f, 0.f, 0.f};

    for (int ng = 0; ng < 4; ++ng) {
        const int n = ng * 16 + colr;

        // B-frag g: leaky(gw_s*(yl + yon) + gw_t)
        s16x8 bg;
        #pragma unroll
        for (int jx = 0; jx < 8; ++jx) {
            float y = yon_s[8 * q + jx][n] + ylv[jx];
            float a = gwsv[jx] * y + gwtv[jx];
            bg[jx] = f2bf(a > 0.f ? a : 0.2f * a);
        }

        f32x4 zlo, zhi;
        zlo[0] = b2i[0]; zlo[1] = b2i[1]; zlo[2] = b2i[2]; zlo[3] = b2i[3];
        zhi[0] = b2i[4]; zhi[1] = b2i[5]; zhi[2] = b2i[6]; zhi[3] = b2i[7];
        zlo = __builtin_amdgcn_mfma_f32_16x16x32_bf16(a_gw2_lo, bg, zlo, 0, 0, 0);
        zhi = __builtin_amdgcn_mfma_f32_16x16x32_bf16(a_gw2_hi, bg, zhi, 0, 0, 0);

        // sigmoid gate * xo  -> bounce ([col][row] bf16)
        #pragma unroll
        for (int ix = 0; ix < 8; ++ix) {
            const int r = ix & 3, row = 4 * q + r + 16 * (ix >> 2);
            const float z = (ix < 4) ? zlo[r] : zhi[r];
            const float w = 1.f / (1.f + __expf(-z));
            bnc_s[wv][colr][row] = f2bf(w * xo_s[row][n]);
        }
        __threadfence_block();
        s16x8 bga = *(const s16x8*)&bnc_s[wv][colr][8 * q];

        f32x4 mlo, mhi;
        #pragma unroll
        for (int r = 0; r < 4; ++r) { mlo[r] = tpos_s[4 * q + r][n]; mhi[r] = tpos_s[4 * q + r + 16][n]; }
        mlo = __builtin_amdgcn_mfma_f32_16x16x32_bf16(a_gm1_lo, bga, mlo, 0, 0, 0);
        mhi = __builtin_amdgcn_mfma_f32_16x16x32_bf16(a_gm1_hi, bga, mhi, 0, 0, 0);

        // relu -> bounce -> m1 B-frag
        #pragma unroll
        for (int ix = 0; ix < 8; ++ix) {
            const int r = ix & 3, row = 4 * q + r + 16 * (ix >> 2);
            float v = (ix < 4) ? mlo[r] : mhi[r];
            bnc_s[wv][colr][row] = f2bf(v > 0.f ? v : 0.f);
        }
        __threadfence_block();
        s16x8 bm1 = *(const s16x8*)&bnc_s[wv][colr][8 * q];

        f32x4 plo, phi;
        plo[0] = t2i[0]; plo[1] = t2i[1]; plo[2] = t2i[2]; plo[3] = t2i[3];
        phi[0] = t2i[4]; phi[1] = t2i[5]; phi[2] = t2i[6]; phi[3] = t2i[7];
        plo = __builtin_amdgcn_mfma_f32_16x16x32_bf16(a_gm2_lo, bm1, plo, 0, 0, 0);
        phi = __builtin_amdgcn_mfma_f32_16x16x32_bf16(a_gm2_hi, bm1, phi, 0, 0, 0);

        #pragma unroll
        for (int ix = 0; ix < 8; ++ix) {
            const int r = ix & 3;
            float v = (ix < 4) ? plo[r] : phi[r];
            rmax[ix] = fmaxf(rmax[ix], v > 0.f ? v : 0.f);
        }
    }

    // max over the 16 cols (n within group already folded via ng loop)
    #pragma unroll
    for (int ix = 0; ix < 8; ++ix) {
        float v = rmax[ix];
        v = fmaxf(v, __shfl_xor(v, 1));
        v = fmaxf(v, __shfl_xor(v, 2));
        v = fmaxf(v, __shfl_xor(v, 4));
        v = fmaxf(v, __shfl_xor(v, 8));
        rmax[ix] = v;
    }
    if (colr == 0) {
        #pragma unroll
        for (int ix = 0; ix < 8; ++ix)
            gp_s[wv][4 * q + (ix & 3) + 16 * (ix >> 2)] = rmax[ix];
    }
    __threadfence_block();

    // ---- Phase B (fp32, one m per wave; lane = template point n) ----
    const int n = lane;
    float num = 0.f;
    #pragma unroll
    for (int c = 0; c < NF; ++c) num += xo_s[c][n] * xl_s[c][mj];
    float cosv = num / fmaxf(na_s[n] * nb_s[mj], 1e-8f);
    float mv = cosv; int mi = n;
    #pragma unroll
    for (int s = 32; s > 0; s >>= 1) {
        float ov = __shfl_xor(mv, s);
        int   oi = __shfl_xor(mi, s);
        if (ov > mv || (ov == mv && oi < mi)) { mv = ov; mi = oi; }
    }

    const int oc = lane & 31;
    float h1;
    {
        const float* w = mlp_w1 + oc * 68;
        float acc = w[0] * mv;
        #pragma unroll
        for (int k = 0; k < 3; ++k)  acc += w[1 + k]  * txyz_s[k][mi];
        #pragma unroll
        for (int c = 0; c < 32; ++c) acc += w[4 + c]  * xo_s[c][mi];
        #pragma unroll
        for (int c = 0; c < 32; ++c) acc += w[36 + c] * xl_s[c][mj];
        acc = mlp_s1[oc] * acc + mlp_t1[oc];
        h1 = acc > 0.f ? acc : 0.f;
    }
    float h2;
    {
        const float* w = mlp_w2 + oc * 32;
        float acc = 0.f;
        #pragma unroll
        for (int c = 0; c < 32; ++c) acc += w[c] * __shfl(h1, c);
        acc = mlp_s2[oc] * acc + mlp_t2[oc];
        h2 = acc > 0.f ? acc : 0.f;
    }
    float o1;
    {
        const float* w = fl_w1 + lane * 64;
        float acc = 0.f;
        #pragma unroll
        for (int c = 0; c < 32; ++c) acc += w[c]      * __shfl(h2, c);
        #pragma unroll
        for (int c = 0; c < 32; ++c) acc += w[32 + c] * gp_s[mj][c];
        acc = fl_s1[lane] * acc + fl_t1[lane];
        o1 = acc > 0.f ? acc : 0.f;
    }
    {
        const float* w = fl_w2 + lane * 64;
        float acc = fl_b2[lane];
        #pragma unroll
        for (int c = 0; c < 64; ++c) acc += w[c] * __shfl(o1, c);
        out[(size_t)b * 64 * NN2 + (size_t)lane * NN2 + m] = acc;
    }
}

extern "C" void kernel_launch(void* const* d_in, const int* in_sizes, int n_in,
                              void* d_out, int out_size, void* d_ws, size_t ws_size,
                              hipStream_t stream) {
    const float* xl     = (const float*)d_in[0];
    const float* xo     = (const float*)d_in[1];
    const float* txyz   = (const float*)d_in[2];
    const float* mlp_w1 = (const float*)d_in[3];
    const float* mlp_s1 = (const float*)d_in[4];
    const float* mlp_t1 = (const float*)d_in[5];
    const float* mlp_w2 = (const float*)d_in[6];
    const float* mlp_s2 = (const float*)d_in[7];
    const float* mlp_t2 = (const float*)d_in[8];
    const float* gw_w1  = (const float*)d_in[9];
    const float* gw_b1  = (const float*)d_in[10];
    const float* gw_s   = (const float*)d_in[11];
    const float* gw_t   = (const float*)d_in[12];
    const float* gw_w2  = (const float*)d_in[13];
    const float* gw_b2  = (const float*)d_in[14];
    const float* gm_w1  = (const float*)d_in[15];
    const float* gm_s1  = (const float*)d_in[16];
    const float* gm_t1  = (const float*)d_in[17];
    const float* gm_w2  = (const float*)d_in[18];
    const float* gm_s2  = (const float*)d_in[19];
    const float* gm_t2  = (const float*)d_in[20];
    const float* fl_w1  = (const float*)d_in[21];
    const float* fl_s1  = (const float*)d_in[22];
    const float* fl_t1  = (const float*)d_in[23];
    const float* fl_w2  = (const float*)d_in[24];
    const float* fl_b2  = (const float*)d_in[25];
    float* outp = (float*)d_out;

    const int B = in_sizes[0] / (NF * NN2);   // 128
    v2b_fused<<<dim3(B * 32), 256, 0, stream>>>(
        xl, xo, txyz,
        mlp_w1, mlp_s1, mlp_t1, mlp_w2, mlp_s2, mlp_t2,
        gw_w1, gw_b1, gw_s, gw_t, gw_w2, gw_b2,
        gm_w1, gm_s1, gm_t1, gm_w2, gm_s2, gm_t2,
        fl_w1, fl_s1, fl_t1, fl_w2, fl_b2,
        outp);
}

// Round 10
// 253.383 us; speedup vs baseline: 2.8943x; 1.2027x over previous
//
#include <hip/hip_runtime.h>

#define NF   32
#define NN1  64
#define NN2  128
#define P    66   // pitch: bank=(2*row+col)%32 -> exactly 2-way for our (q,colr) patterns

typedef float f32x4 __attribute__((ext_vector_type(4)));
typedef short s16x8 __attribute__((ext_vector_type(8)));
typedef unsigned int u32;

__device__ __forceinline__ short f2bf(float f) {   // fp32 -> bf16 bits, RNE
    u32 u = __float_as_uint(f);
    return (short)((u + 0x7FFFu + ((u >> 16) & 1u)) >> 16);
}
__device__ __forceinline__ u32 pack2(float a, float b) {
    return (u32)(unsigned short)f2bf(a) | ((u32)(unsigned short)f2bf(b) << 16);
}

// MFMA Phase A, lean-register version (fit the 64-VGPR bucket; R9 lesson).
// A-frags + folded consts live in LDS; D->B redistribution via ds_bpermute within
// 4-lane groups (no LDS bounce; R9's 4.8M bank conflicts came from it).
// Layouts (validated R9, absmax 1.95e-3): A: lane=(colr,q) holds A[colr(+16)][8q+j];
// B: B[8q+j][colr]; C/D: col=lane&15, row=4*(lane>>4)+reg (+16 for hi frag).
__global__ __launch_bounds__(256, 4)
void v2b_fused(const float* __restrict__ xl,    // (B,32,128)
               const float* __restrict__ xo,    // (B,32,64)
               const float* __restrict__ txyz,  // (B,64,3)
               const float* __restrict__ mlp_w1, const float* __restrict__ mlp_s1, const float* __restrict__ mlp_t1,
               const float* __restrict__ mlp_w2, const float* __restrict__ mlp_s2, const float* __restrict__ mlp_t2,
               const float* __restrict__ gw_w1, const float* __restrict__ gw_b1,
               const float* __restrict__ gw_s,  const float* __restrict__ gw_t,
               const float* __restrict__ gw_w2, const float* __restrict__ gw_b2,
               const float* __restrict__ gm_w1, const float* __restrict__ gm_s1, const float* __restrict__ gm_t1,
               const float* __restrict__ gm_w2, const float* __restrict__ gm_s2, const float* __restrict__ gm_t2,
               const float* __restrict__ fl_w1, const float* __restrict__ fl_s1, const float* __restrict__ fl_t1,
               const float* __restrict__ fl_w2, const float* __restrict__ fl_b2,
               float* __restrict__ out)
{
    __shared__ float xo_s[NF][P];
    __shared__ float yon_s[NF][P];     // -(gw_w1 . xo)
    __shared__ float tpos_s[NF][P];    // gm_t1 + gm_s1*(gm_w1[:,0:3] . txyz)
    __shared__ float txyz_s[3][NN1];
    __shared__ float xl_s[NF][4];
    __shared__ float ylT_s[4][NF];     // gw_w1 . xl + gw_b1, [m][c]
    __shared__ float na_s[NN1];
    __shared__ float nb_s[4];
    __shared__ float gp_s[4][NF];
    __shared__ float gws_s[NF], gwt_s[NF], gwb2_s[NF], gmt2_s[NF];
    __shared__ s16x8 afrag_s[6][64];   // 0/1: gw2 lo/hi, 2/3: s1*gm1 lo/hi, 4/5: s2*gm2 lo/hi

    const int b    = blockIdx.x >> 5;
    const int m0   = (blockIdx.x & 31) * 4;
    const int tid  = threadIdx.x;
    const int lane = tid & 63;
    const int wv   = tid >> 6;
    const int colr = lane & 15;
    const int q    = lane >> 4;

    // ---- stage ----
    const float* xob = xo + (size_t)b * NF * NN1;
    for (int i = tid; i < NF * NN1; i += 256) xo_s[i >> 6][i & 63] = xob[i];
    const float* tb = txyz + (size_t)b * NN1 * 3;
    if (tid < NN1 * 3) { int nn = tid / 3, k = tid % 3; txyz_s[k][nn] = tb[tid]; }
    if (tid < NF * 4) {
        int c = tid >> 2, j = tid & 3;
        xl_s[c][j] = xl[(size_t)b * NF * NN2 + c * NN2 + m0 + j];
    }
    if (tid < NF) {
        gws_s[tid]  = gw_s[tid];
        gwt_s[tid]  = gw_t[tid];
        gwb2_s[tid] = gw_b2[tid];
        gmt2_s[tid] = gm_t2[tid];
    }
    // A-frags (no staged-data dependency)
    for (int f = wv; f < 6; f += 4) {
        const int row = (f & 1) ? colr + 16 : colr;
        s16x8 a;
        if (f < 2) {
            #pragma unroll
            for (int j = 0; j < 8; ++j) a[j] = f2bf(gw_w2[row * 32 + 8 * q + j]);
        } else if (f < 4) {
            const float s1 = gm_s1[row];
            #pragma unroll
            for (int j = 0; j < 8; ++j) a[j] = f2bf(s1 * gm_w1[row * 35 + 3 + 8 * q + j]);
        } else {
            const float s2 = gm_s2[row];
            #pragma unroll
            for (int j = 0; j < 8; ++j) a[j] = f2bf(s2 * gm_w2[row * 32 + 8 * q + j]);
        }
        afrag_s[f][lane] = a;
    }
    __syncthreads();

    // ---- block precompute (fp32 exact) ----
    for (int i = tid; i < NF * NN1; i += 256) {
        const int o = i >> 6, nn = i & 63;
        float s = 0.f;
        #pragma unroll
        for (int c = 0; c < NF; ++c) s += gw_w1[o * 32 + c] * xo_s[c][nn];
        yon_s[o][nn] = -s;
        float tp = gm_w1[o * 35 + 0] * txyz_s[0][nn]
                 + gm_w1[o * 35 + 1] * txyz_s[1][nn]
                 + gm_w1[o * 35 + 2] * txyz_s[2][nn];
        tpos_s[o][nn] = gm_s1[o] * tp + gm_t1[o];
    }
    if (tid < 128) {
        const int o = tid >> 2, j = tid & 3;
        float s = gw_b1[o];
        #pragma unroll
        for (int c = 0; c < NF; ++c) s += gw_w1[o * 32 + c] * xl_s[c][j];
        ylT_s[j][o] = s;
    } else if (tid < 192) {
        const int nn = tid - 128;
        float s = 0.f;
        #pragma unroll
        for (int c = 0; c < NF; ++c) { float v = xo_s[c][nn]; s += v * v; }
        na_s[nn] = sqrtf(s);
    } else if (tid < 196) {
        const int j = tid - 192;
        float s = 0.f;
        #pragma unroll
        for (int c = 0; c < NF; ++c) { float v = xl_s[c][j]; s += v * v; }
        nb_s[j] = sqrtf(s);
    }
    __syncthreads();

    const int mj = wv;
    const int m  = m0 + wv;
    const int lA = colr + ((q & 1) << 5);   // redistribution source lanes
    const int lB = lA + 16;

    float rmax[8] = {0.f, 0.f, 0.f, 0.f, 0.f, 0.f, 0.f, 0.f};

    for (int ng = 0; ng < 4; ++ng) {
        const int n = ng * 16 + colr;

        // ---- B-frag g = leaky(gw_s*(yl+yon)+gw_t) ----
        s16x8 bg;
        #pragma unroll
        for (int j = 0; j < 8; ++j) {
            const int k = 8 * q + j;
            float y = yon_s[k][n] + ylT_s[mj][k];
            float a = gws_s[k] * y + gwt_s[k];
            bg[j] = f2bf(a > 0.f ? a : 0.2f * a);
        }

        // ---- gate: z = gw_w2 @ g + b2 ----
        f32x4 zlo, zhi;
        #pragma unroll
        for (int r = 0; r < 4; ++r) { zlo[r] = gwb2_s[4 * q + r]; zhi[r] = gwb2_s[4 * q + r + 16]; }
        zlo = __builtin_amdgcn_mfma_f32_16x16x32_bf16(afrag_s[0][lane], bg, zlo, 0, 0, 0);
        zhi = __builtin_amdgcn_mfma_f32_16x16x32_bf16(afrag_s[1][lane], bg, zhi, 0, 0, 0);

        // ---- sigmoid(z) * xo, pack, redistribute -> B-frag ----
        float dlo[4], dhi[4];
        #pragma unroll
        for (int r = 0; r < 4; ++r) {
            float wlo = 1.f / (1.f + __expf(-zlo[r]));
            float whi = 1.f / (1.f + __expf(-zhi[r]));
            dlo[r] = wlo * xo_s[4 * q + r][n];
            dhi[r] = whi * xo_s[4 * q + r + 16][n];
        }
        u32 plo01 = pack2(dlo[0], dlo[1]), plo23 = pack2(dlo[2], dlo[3]);
        u32 phi01 = pack2(dhi[0], dhi[1]), phi23 = pack2(dhi[2], dhi[3]);
        u32 w0, w1, w2, w3;
        {
            u32 al0 = __shfl((int)plo01, lA), ah0 = __shfl((int)phi01, lA);
            u32 al1 = __shfl((int)plo23, lA), ah1 = __shfl((int)phi23, lA);
            u32 bl0 = __shfl((int)plo01, lB), bh0 = __shfl((int)phi01, lB);
            u32 bl1 = __shfl((int)plo23, lB), bh1 = __shfl((int)phi23, lB);
            w0 = (q < 2) ? al0 : ah0;  w1 = (q < 2) ? al1 : ah1;
            w2 = (q < 2) ? bl0 : bh0;  w3 = (q < 2) ? bl1 : bh1;
        }
        s16x8 bga;
        bga[0] = (short)w0; bga[1] = (short)(w0 >> 16);
        bga[2] = (short)w1; bga[3] = (short)(w1 >> 16);
        bga[4] = (short)w2; bga[5] = (short)(w2 >> 16);
        bga[6] = (short)w3; bga[7] = (short)(w3 >> 16);

        // ---- gm1: m1 = relu(s1*(W@feat)+t1), txyz part in C-init ----
        f32x4 mlo, mhi;
        #pragma unroll
        for (int r = 0; r < 4; ++r) { mlo[r] = tpos_s[4 * q + r][n]; mhi[r] = tpos_s[4 * q + r + 16][n]; }
        mlo = __builtin_amdgcn_mfma_f32_16x16x32_bf16(afrag_s[2][lane], bga, mlo, 0, 0, 0);
        mhi = __builtin_amdgcn_mfma_f32_16x16x32_bf16(afrag_s[3][lane], bga, mhi, 0, 0, 0);

        // ---- relu, pack, redistribute -> B-frag m1 ----
        u32 qlo01 = pack2(fmaxf(mlo[0], 0.f), fmaxf(mlo[1], 0.f));
        u32 qlo23 = pack2(fmaxf(mlo[2], 0.f), fmaxf(mlo[3], 0.f));
        u32 qhi01 = pack2(fmaxf(mhi[0], 0.f), fmaxf(mhi[1], 0.f));
        u32 qhi23 = pack2(fmaxf(mhi[2], 0.f), fmaxf(mhi[3], 0.f));
        {
            u32 al0 = __shfl((int)qlo01, lA), ah0 = __shfl((int)qhi01, lA);
            u32 al1 = __shfl((int)qlo23, lA), ah1 = __shfl((int)qhi23, lA);
            u32 bl0 = __shfl((int)qlo01, lB), bh0 = __shfl((int)qhi01, lB);
            u32 bl1 = __shfl((int)qlo23, lB), bh1 = __shfl((int)qhi23, lB);
            w0 = (q < 2) ? al0 : ah0;  w1 = (q < 2) ? al1 : ah1;
            w2 = (q < 2) ? bl0 : bh0;  w3 = (q < 2) ? bl1 : bh1;
        }
        s16x8 bm1;
        bm1[0] = (short)w0; bm1[1] = (short)(w0 >> 16);
        bm1[2] = (short)w1; bm1[3] = (short)(w1 >> 16);
        bm1[4] = (short)w2; bm1[5] = (short)(w2 >> 16);
        bm1[6] = (short)w3; bm1[7] = (short)(w3 >> 16);

        // ---- gm2: relu(s2*(W@m1)+t2), fold into running max ----
        f32x4 plo, phi;
        #pragma unroll
        for (int r = 0; r < 4; ++r) { plo[r] = gmt2_s[4 * q + r]; phi[r] = gmt2_s[4 * q + r + 16]; }
        plo = __builtin_amdgcn_mfma_f32_16x16x32_bf16(afrag_s[4][lane], bm1, plo, 0, 0, 0);
        phi = __builtin_amdgcn_mfma_f32_16x16x32_bf16(afrag_s[5][lane], bm1, phi, 0, 0, 0);
        #pragma unroll
        for (int r = 0; r < 4; ++r) {
            rmax[r]     = fmaxf(rmax[r],     fmaxf(plo[r], 0.f));
            rmax[r + 4] = fmaxf(rmax[r + 4], fmaxf(phi[r], 0.f));
        }
    }

    // ---- reduce max over the 16 cols, write gpool ----
    #pragma unroll
    for (int ix = 0; ix < 8; ++ix) {
        float v = rmax[ix];
        v = fmaxf(v, __shfl_xor(v, 1));
        v = fmaxf(v, __shfl_xor(v, 2));
        v = fmaxf(v, __shfl_xor(v, 4));
        v = fmaxf(v, __shfl_xor(v, 8));
        rmax[ix] = v;
    }
    if (colr == 0) {
        #pragma unroll
        for (int ix = 0; ix < 8; ++ix)
            gp_s[wv][4 * q + (ix & 3) + 16 * (ix >> 2)] = rmax[ix];
    }

    // ---- Phase B (fp32; same wave wrote gp_s[mj] -> no barrier needed) ----
    const int n = lane;
    float num = 0.f;
    #pragma unroll
    for (int c = 0; c < NF; ++c) num += xo_s[c][n] * xl_s[c][mj];
    float cosv = num / fmaxf(na_s[n] * nb_s[mj], 1e-8f);
    float mv = cosv; int mi = n;
    #pragma unroll
    for (int s = 32; s > 0; s >>= 1) {
        float ov = __shfl_xor(mv, s);
        int   oi = __shfl_xor(mi, s);
        if (ov > mv || (ov == mv && oi < mi)) { mv = ov; mi = oi; }
    }

    const int oc = lane & 31;
    float h1;
    {
        const float* w = mlp_w1 + oc * 68;
        float acc = w[0] * mv;
        #pragma unroll
        for (int k = 0; k < 3; ++k)  acc += w[1 + k]  * txyz_s[k][mi];
        #pragma unroll
        for (int c = 0; c < 32; ++c) acc += w[4 + c]  * xo_s[c][mi];
        #pragma unroll
        for (int c = 0; c < 32; ++c) acc += w[36 + c] * xl_s[c][mj];
        acc = mlp_s1[oc] * acc + mlp_t1[oc];
        h1 = acc > 0.f ? acc : 0.f;
    }
    float h2;
    {
        const float* w = mlp_w2 + oc * 32;
        float acc = 0.f;
        #pragma unroll
        for (int c = 0; c < 32; ++c) acc += w[c] * __shfl(h1, c);
        acc = mlp_s2[oc] * acc + mlp_t2[oc];
        h2 = acc > 0.f ? acc : 0.f;
    }
    float o1;
    {
        const float* w = fl_w1 + lane * 64;
        float acc = 0.f;
        #pragma unroll
        for (int c = 0; c < 32; ++c) acc += w[c]      * __shfl(h2, c);
        #pragma unroll
        for (int c = 0; c < 32; ++c) acc += w[32 + c] * gp_s[mj][c];
        acc = fl_s1[lane] * acc + fl_t1[lane];
        o1 = acc > 0.f ? acc : 0.f;
    }
    {
        const float* w = fl_w2 + lane * 64;
        float acc = fl_b2[lane];
        #pragma unroll
        for (int c = 0; c < 64; ++c) acc += w[c] * __shfl(o1, c);
        out[(size_t)b * 64 * NN2 + (size_t)lane * NN2 + m] = acc;
    }
}

extern "C" void kernel_launch(void* const* d_in, const int* in_sizes, int n_in,
                              void* d_out, int out_size, void* d_ws, size_t ws_size,
                              hipStream_t stream) {
    const float* xl     = (const float*)d_in[0];
    const float* xo     = (const float*)d_in[1];
    const float* txyz   = (const float*)d_in[2];
    const float* mlp_w1 = (const float*)d_in[3];
    const float* mlp_s1 = (const float*)d_in[4];
    const float* mlp_t1 = (const float*)d_in[5];
    const float* mlp_w2 = (const float*)d_in[6];
    const float* mlp_s2 = (const float*)d_in[7];
    const float* mlp_t2 = (const float*)d_in[8];
    const float* gw_w1  = (const float*)d_in[9];
    const float* gw_b1  = (const float*)d_in[10];
    const float* gw_s   = (const float*)d_in[11];
    const float* gw_t   = (const float*)d_in[12];
    const float* gw_w2  = (const float*)d_in[13];
    const float* gw_b2  = (const float*)d_in[14];
    const float* gm_w1  = (const float*)d_in[15];
    const float* gm_s1  = (const float*)d_in[16];
    const float* gm_t1  = (const float*)d_in[17];
    const float* gm_w2  = (const float*)d_in[18];
    const float* gm_s2  = (const float*)d_in[19];
    const float* gm_t2  = (const float*)d_in[20];
    const float* fl_w1  = (const float*)d_in[21];
    const float* fl_s1  = (const float*)d_in[22];
    const float* fl_t1  = (const float*)d_in[23];
    const float* fl_w2  = (const float*)d_in[24];
    const float* fl_b2  = (const float*)d_in[25];
    float* outp = (float*)d_out;

    const int B = in_sizes[0] / (NF * NN2);   // 128
    v2b_fused<<<dim3(B * 32), 256, 0, stream>>>(
        xl, xo, txyz,
        mlp_w1, mlp_s1, mlp_t1, mlp_w2, mlp_s2, mlp_t2,
        gw_w1, gw_b1, gw_s, gw_t, gw_w2, gw_b2,
        gm_w1, gm_s1, gm_t1, gm_w2, gm_s2, gm_t2,
        fl_w1, fl_s1, fl_t1, fl_w2, fl_b2,
        outp);
}